// Round 1
// baseline (129.331 us; speedup 1.0000x reference)
//
#include <hip/hip_runtime.h>
#include <math.h>

#define B_ 32
#define P_ 1000
#define T_ 16
#define D_ 78
#define O_ 72
#define BIGC 100000000.0f

// ---------------- Kernel A: distances, line-iou, per-batch maxes ----------------
__global__ void kA(const float* __restrict__ preds, const float* __restrict__ targets,
                   const int* __restrict__ imgw_p, const int* __restrict__ imgh_p,
                   float* __restrict__ dist, float* __restrict__ liou,
                   unsigned int* __restrict__ dmax, unsigned int* __restrict__ smax,
                   unsigned int* __restrict__ tmax) {
    __shared__ float t_off_s[T_ * O_];
    __shared__ float clen_s[T_];
    __shared__ float red[256];

    const int b = blockIdx.y;
    const int p = blockIdx.x * 256 + threadIdx.x;
    const float w = (float)(imgw_p[0] - 1);
    const float h = (float)(imgh_p[0] - 1);
    const float imgwf = (float)imgw_p[0];

    // stage scaled target offsets for this batch
    for (int i = threadIdx.x; i < T_ * O_; i += 256) {
        int t = i / O_, o = i - t * O_;
        t_off_s[i] = targets[(b * T_ + t) * D_ + 6 + o] * w;
    }
    __syncthreads();
    if (threadIdx.x < T_) {
        int t = threadIdx.x;
        int c = 0;
        for (int o = 0; o < O_; ++o) {
            float v = t_off_s[t * O_ + o];
            c += (v >= 0.f && v < imgwf) ? 1 : 0;
        }
        clen_s[t] = fmaxf((float)c, 1.f);
    }
    __syncthreads();

    float ldm = 0.f, lsm = 0.f, ltm = 0.f;
    if (p < P_) {
        const float* pr = preds + (size_t)(b * P_ + p) * D_;
        float ps0 = pr[2] * h, ps1 = pr[3] * w, pth = pr[4];

        float dacc[T_], oacc[T_], uacc[T_];
#pragma unroll
        for (int t = 0; t < T_; ++t) { dacc[t] = 0.f; oacc[t] = 0.f; uacc[t] = 0.f; }

        for (int o = 0; o < O_; ++o) {
            float po = pr[6 + o] * w;
            float px1 = po - 15.f, px2 = po + 15.f;
#pragma unroll
            for (int t = 0; t < T_; ++t) {
                float to = t_off_s[t * O_ + o];
                bool valid = (to >= 0.f) && (to < imgwf);
                if (valid) {
                    dacc[t] += fabsf(po - to);
                    float tx1 = to - 15.f, tx2 = to + 15.f;
                    oacc[t] += fminf(px2, tx2) - fmaxf(px1, tx1);
                    uacc[t] += fmaxf(px2, tx2) - fminf(px1, tx1);
                }
            }
        }

#pragma unroll
        for (int t = 0; t < T_; ++t) {
            float d = dacc[t] / clen_s[t];
            dist[(size_t)(b * T_ + t) * P_ + p] = d;
            ldm = fmaxf(ldm, d);
            float li = oacc[t] / (uacc[t] + 1e-9f);
            if (li != li) li = 0.f;   // nan_to_num
            liou[(size_t)(b * T_ + t) * P_ + p] = li;

            const float* tr = targets + (size_t)(b * T_ + t) * D_;
            float ts0 = tr[2] * h, ts1 = tr[3] * w;
            float d0 = ps0 - ts0, d1 = ps1 - ts1;
            float sd = sqrtf(d0 * d0 + d1 * d1);
            lsm = fmaxf(lsm, sd);
            float td = fabsf(pth - tr[4]) * 180.f;
            ltm = fmaxf(ltm, td);
        }
    }

    // block max-reductions -> atomicMax (uint bits, all values >= 0)
    red[threadIdx.x] = ldm; __syncthreads();
    for (int s = 128; s; s >>= 1) {
        if (threadIdx.x < s) red[threadIdx.x] = fmaxf(red[threadIdx.x], red[threadIdx.x + s]);
        __syncthreads();
    }
    if (threadIdx.x == 0) atomicMax(&dmax[b], __float_as_uint(red[0]));
    __syncthreads();

    red[threadIdx.x] = lsm; __syncthreads();
    for (int s = 128; s; s >>= 1) {
        if (threadIdx.x < s) red[threadIdx.x] = fmaxf(red[threadIdx.x], red[threadIdx.x + s]);
        __syncthreads();
    }
    if (threadIdx.x == 0) atomicMax(&smax[b], __float_as_uint(red[0]));
    __syncthreads();

    red[threadIdx.x] = ltm; __syncthreads();
    for (int s = 128; s; s >>= 1) {
        if (threadIdx.x < s) red[threadIdx.x] = fmaxf(red[threadIdx.x], red[threadIdx.x + s]);
        __syncthreads();
    }
    if (threadIdx.x == 0) atomicMax(&tmax[b], __float_as_uint(red[0]));
}

// ---------------- Kernel B: total cost ----------------
__global__ void kB(const float* __restrict__ preds, const float* __restrict__ targets,
                   const int* __restrict__ masks,
                   const int* __restrict__ imgw_p, const int* __restrict__ imgh_p,
                   const float* __restrict__ dist,
                   const unsigned int* __restrict__ dmaxs, const unsigned int* __restrict__ smaxs,
                   const unsigned int* __restrict__ tmaxs,
                   float* __restrict__ cost) {
    __shared__ float ts0s[T_], ts1s[T_], tths[T_];
    __shared__ int labs[T_], mks[T_];

    const int b = blockIdx.y;
    const int p = blockIdx.x * 256 + threadIdx.x;
    const float w = (float)(imgw_p[0] - 1);
    const float h = (float)(imgh_p[0] - 1);

    if (threadIdx.x < T_) {
        int t = threadIdx.x;
        const float* tr = targets + (size_t)(b * T_ + t) * D_;
        ts0s[t] = tr[2] * h;
        ts1s[t] = tr[3] * w;
        tths[t] = tr[4];
        int lab = (int)tr[1];           // trunc toward zero, matches astype(int32)
        labs[t] = lab < 0 ? 0 : (lab > 1 ? 1 : lab);
        mks[t] = masks[b * T_ + t];
    }
    __syncthreads();
    if (p >= P_) return;

    float dmaxv = fmaxf(__uint_as_float(dmaxs[b]), 1e-8f);
    float smaxv = fmaxf(__uint_as_float(smaxs[b]), 1e-8f);
    float tmaxv = fmaxf(__uint_as_float(tmaxs[b]), 1e-8f);

    const float* pr = preds + (size_t)(b * P_ + p) * D_;
    float fc[2];
#pragma unroll
    for (int c = 0; c < 2; ++c) {
        float x = pr[c];
        float pc = 1.f / (1.f + expf(-x));
        float neg = -logf(1.f - pc + 1e-12f) * 0.75f * pc * pc;
        float pos = -logf(pc + 1e-12f) * 0.25f * (1.f - pc) * (1.f - pc);
        fc[c] = pos - neg;
    }
    float ps0 = pr[2] * h, ps1 = pr[3] * w, pth = pr[4];

#pragma unroll
    for (int t = 0; t < T_; ++t) {
        float d = dist[(size_t)(b * T_ + t) * P_ + p];
        float dsc = 1.f - d / dmaxv + 0.01f;
        float d0 = ps0 - ts0s[t], d1 = ps1 - ts1s[t];
        float sd = sqrtf(d0 * d0 + d1 * d1);
        float ssc = 1.f - sd / smaxv + 0.01f;
        float td = fabsf(pth - tths[t]) * 180.f;
        float tsc = 1.f - td / tmaxv + 0.01f;
        float reg = fmaxf(dsc, 1e-3f) * fmaxf(ssc, 1e-3f) * fmaxf(tsc, 1e-3f);
        float c = -(reg * reg) * 3.f + fc[labs[t]];
        if (mks[t] <= 0) c = BIGC;
        cost[(size_t)(b * T_ + t) * P_ + p] = c;
    }
}

// ---------------- Kernel C: per-(b,t) top-4 + dynamic-k selection ----------------
__global__ void kC(const float* __restrict__ liou, const float* __restrict__ cost,
                   const int* __restrict__ masks, unsigned int* __restrict__ bits) {
    const int gtid = blockIdx.x * blockDim.x + threadIdx.x;
    const int wid = gtid >> 6;        // one wave per (b,t)
    const int lane = threadIdx.x & 63;
    if (wid >= B_ * T_) return;
    const int b = wid / T_, t = wid - b * T_;

    const float* lrow = liou + (size_t)(b * T_ + t) * P_;
    const float* crow = cost + (size_t)(b * T_ + t) * P_;

    float lv[16], cv[16];
#pragma unroll
    for (int i = 0; i < 16; ++i) {
        int p = lane + 64 * i;
        bool ok = p < P_;
        lv[i] = ok ? lrow[p] : -INFINITY;
        cv[i] = ok ? crow[p] : INFINITY;
    }

    // sum of top-4 liou (wave argmax, 4 rounds)
    float sum = 0.f;
    for (int r = 0; r < 4; ++r) {
        float bv = -INFINITY; int bi = 0x7fffffff;
#pragma unroll
        for (int i = 0; i < 16; ++i) {
            if (lv[i] > bv) { bv = lv[i]; bi = lane + 64 * i; }
        }
        for (int off = 32; off; off >>= 1) {
            float ov = __shfl_xor(bv, off, 64);
            int oi = __shfl_xor(bi, off, 64);
            if (ov > bv || (ov == bv && oi < bi)) { bv = ov; bi = oi; }
        }
        sum += bv;
        if ((bi & 63) == lane) lv[bi >> 6] = -INFINITY;
    }
    int dk = 0;
    if (masks[b * T_ + t] > 0) {
        dk = (int)sum;                // trunc toward zero == astype(int32)
        if (dk < 1) dk = 1;
        if (dk > 4) dk = 4;
    }

    // top-4 lowest cost, tie-break lower p (lax.top_k stable semantics)
    int selp[4];
#pragma unroll
    for (int r = 0; r < 4; ++r) {
        float bv = INFINITY; int bi = 0x7fffffff;
#pragma unroll
        for (int i = 0; i < 16; ++i) {
            if (cv[i] < bv) { bv = cv[i]; bi = lane + 64 * i; }
        }
        for (int off = 32; off; off >>= 1) {
            float ov = __shfl_xor(bv, off, 64);
            int oi = __shfl_xor(bi, off, 64);
            if (ov < bv || (ov == bv && oi < bi)) { bv = ov; bi = oi; }
        }
        selp[r] = bi;
        if ((bi & 63) == lane) cv[bi >> 6] = INFINITY;
    }

    if (lane == 0) {
#pragma unroll
        for (int j = 0; j < 4; ++j) {
            if (j < dk) atomicOr(&bits[b * P_ + selp[j]], 1u << t);
        }
    }
}

// ---------------- Kernel D: conflict resolution + output ----------------
__global__ void kD(const unsigned int* __restrict__ bits, const float* __restrict__ cost,
                   int* __restrict__ out) {
    const int idx = blockIdx.x * 256 + threadIdx.x;
    if (idx >= B_ * P_) return;
    const int b = idx / P_, p = idx - b * P_;
    unsigned int m = bits[idx];
    int matched = -1;
    if (m) {
        if (__popc(m) == 1) {
            matched = __ffs(m) - 1;
        } else {
            float best = INFINITY;
#pragma unroll
            for (int t = 0; t < T_; ++t) {
                if ((m >> t) & 1u) {
                    float c = cost[(size_t)(b * T_ + t) * P_ + p];
                    if (c < best) { best = c; matched = t; }   // strict < : first-min tie-break
                }
            }
        }
    }
    out[idx] = (matched >= 0) ? 1 : 0;
    out[B_ * P_ + idx] = matched;
}

extern "C" void kernel_launch(void* const* d_in, const int* in_sizes, int n_in,
                              void* d_out, int out_size, void* d_ws, size_t ws_size,
                              hipStream_t stream) {
    const float* preds   = (const float*)d_in[0];
    const float* targets = (const float*)d_in[1];
    const int*   masks   = (const int*)d_in[2];
    const int*   imgw    = (const int*)d_in[3];
    const int*   imgh    = (const int*)d_in[4];
    int* out = (int*)d_out;

    char* ws = (char*)d_ws;
    const size_t SZ = (size_t)B_ * T_ * P_ * sizeof(float);   // 2,048,000 B
    float* dist = (float*)ws;
    float* liou = (float*)(ws + SZ);
    float* cost = (float*)(ws + 2 * SZ);
    unsigned int* dmax = (unsigned int*)(ws + 3 * SZ);        // 32 each
    unsigned int* smax = dmax + 32;
    unsigned int* tmax = dmax + 64;
    unsigned int* bits = (unsigned int*)(ws + 3 * SZ + 512);  // B_*P_ uints

    // zero the atomic-max slots and the match bitmasks (ws is poisoned otherwise)
    hipMemsetAsync(ws + 3 * SZ, 0, 512 + (size_t)B_ * P_ * sizeof(unsigned int), stream);

    kA<<<dim3(4, 32), 256, 0, stream>>>(preds, targets, imgw, imgh, dist, liou, dmax, smax, tmax);
    kB<<<dim3(4, 32), 256, 0, stream>>>(preds, targets, masks, imgw, imgh, dist, dmax, smax, tmax, cost);
    kC<<<128, 256, 0, stream>>>(liou, cost, masks, bits);
    kD<<<125, 256, 0, stream>>>(bits, cost, out);
}

// Round 3
// 44.911 us; speedup vs baseline: 2.8797x; 2.8797x over previous
//
#include <hip/hip_runtime.h>
#include <math.h>

#define B_ 32
#define P_ 1000
#define T_ 16
#define D_ 78
#define O_ 72
#define BIGC 100000000.0f

// ---------------- Kernel A: masked-L1 sums -> dist & line-iou, per-batch maxes ----------------
// Identity: for each valid element, ovr = 30 - |po-to|, union = 30 + |po-to|.
// So S = sum(m*|po-to|), cnt = sum(m):  dist = S/max(cnt,1), liou = (30c - S)/(30c + S + 1e-9).
__global__ __launch_bounds__(256) void kA(
        const float* __restrict__ preds, const float* __restrict__ targets,
        const int* __restrict__ imgw_p, const int* __restrict__ imgh_p,
        float* __restrict__ dist, float* __restrict__ liou,
        unsigned int* __restrict__ dmax, unsigned int* __restrict__ smax,
        unsigned int* __restrict__ tmax) {
    __shared__ float pred_s[64 * 81];        // 64 rows, pad 81 -> conflict-free per-lane rows
    __shared__ float2 tom_s[T_ * O_];        // (t_off*w, mask)
    __shared__ float cnt_s[T_], clen_s[T_], ts0_s[T_], ts1_s[T_], tth_s[T_];
    __shared__ float red[256];

    const int b = blockIdx.y;
    const int p0 = blockIdx.x * 64;
    const int rows = min(64, P_ - p0);
    const float w = (float)(imgw_p[0] - 1);
    const float h = (float)(imgh_p[0] - 1);
    const float imgwf = (float)imgw_p[0];

    // ---- stage preds rows (coalesced float4); scale col 3 and cols>=6 by w ----
    {
        const float4* gbase = (const float4*)(preds + ((size_t)b * P_ + p0) * D_);
        const int n4 = rows * D_ / 4;        // 78*rows always divisible by 4
        for (int i = threadIdx.x; i < n4; i += 256) {
            float4 v = gbase[i];
            int base = i * 4;
            int r = base / D_, c = base - r * D_;
#pragma unroll
            for (int k = 0; k < 4; ++k) {
                int cc = c + k, rr = r;
                if (cc >= D_) { cc -= D_; ++rr; }
                float x = (&v.x)[k];
                if (cc >= 6 || cc == 3) x *= w;   // FIX: col 3 must also be scaled by w
                pred_s[rr * 81 + cc] = x;
            }
        }
    }
    // ---- stage target offsets + masks ----
    for (int i = threadIdx.x; i < T_ * O_; i += 256) {
        int t = i / O_, o = i - t * O_;
        float to = targets[((size_t)b * T_ + t) * D_ + 6 + o] * w;
        float m = (to >= 0.f && to < imgwf) ? 1.f : 0.f;
        tom_s[i] = make_float2(to, m);
    }
    __syncthreads();
    if (threadIdx.x < T_) {
        int t = threadIdx.x;
        float c = 0.f;
        for (int o = 0; o < O_; ++o) c += tom_s[t * O_ + o].y;
        cnt_s[t] = c;
        clen_s[t] = fmaxf(c, 1.f);
        const float* tr = targets + ((size_t)b * T_ + t) * D_;
        ts0_s[t] = tr[2] * h;
        ts1_s[t] = tr[3] * w;
        tth_s[t] = tr[4];
    }
    __syncthreads();

    const int lane = threadIdx.x & 63;
    const int g = threadIdx.x >> 6;          // t-group: t = 4g..4g+3 (wave-uniform)
    const int p = p0 + lane;

    float ldm = 0.f, lsm = 0.f, ltm = 0.f;
    if (p < P_) {
        const float* lrow = pred_s + lane * 81;
        float S0 = 0.f, S1 = 0.f, S2 = 0.f, S3 = 0.f;
        const float2* tg = tom_s + (4 * g) * O_;
#pragma unroll 4
        for (int o = 0; o < O_; ++o) {
            float po = lrow[6 + o];
            float2 a0 = tg[o];
            float2 a1 = tg[O_ + o];
            float2 a2 = tg[2 * O_ + o];
            float2 a3 = tg[3 * O_ + o];
            S0 += a0.y * fabsf(po - a0.x);
            S1 += a1.y * fabsf(po - a1.x);
            S2 += a2.y * fabsf(po - a2.x);
            S3 += a3.y * fabsf(po - a3.x);
        }
        float Sv[4] = {S0, S1, S2, S3};
        float ps0 = lrow[2] * h, ps1 = lrow[3], pth = lrow[4];   // col3 pre-scaled by w (fixed)
#pragma unroll
        for (int j = 0; j < 4; ++j) {
            int t = 4 * g + j;
            float dv = Sv[j] / clen_s[t];
            dist[(size_t)(b * T_ + t) * P_ + p] = dv;
            ldm = fmaxf(ldm, dv);
            float c30 = 30.f * cnt_s[t];
            liou[(size_t)(b * T_ + t) * P_ + p] = (c30 - Sv[j]) / (c30 + Sv[j] + 1e-9f);
            float d0 = ps0 - ts0_s[t], d1 = ps1 - ts1_s[t];
            lsm = fmaxf(lsm, sqrtf(d0 * d0 + d1 * d1));
            ltm = fmaxf(ltm, fabsf(pth - tth_s[t]) * 180.f);
        }
    }

    // ---- block max reductions -> atomicMax (uint bits of nonneg floats) ----
    red[threadIdx.x] = ldm; __syncthreads();
    for (int s = 128; s; s >>= 1) {
        if (threadIdx.x < s) red[threadIdx.x] = fmaxf(red[threadIdx.x], red[threadIdx.x + s]);
        __syncthreads();
    }
    if (threadIdx.x == 0) atomicMax(&dmax[b], __float_as_uint(red[0]));
    __syncthreads();
    red[threadIdx.x] = lsm; __syncthreads();
    for (int s = 128; s; s >>= 1) {
        if (threadIdx.x < s) red[threadIdx.x] = fmaxf(red[threadIdx.x], red[threadIdx.x + s]);
        __syncthreads();
    }
    if (threadIdx.x == 0) atomicMax(&smax[b], __float_as_uint(red[0]));
    __syncthreads();
    red[threadIdx.x] = ltm; __syncthreads();
    for (int s = 128; s; s >>= 1) {
        if (threadIdx.x < s) red[threadIdx.x] = fmaxf(red[threadIdx.x], red[threadIdx.x + s]);
        __syncthreads();
    }
    if (threadIdx.x == 0) atomicMax(&tmax[b], __float_as_uint(red[0]));
}

// ---------------- Kernel B: total cost ----------------
__global__ void kB(const float* __restrict__ preds, const float* __restrict__ targets,
                   const int* __restrict__ masks,
                   const int* __restrict__ imgw_p, const int* __restrict__ imgh_p,
                   const float* __restrict__ dist,
                   const unsigned int* __restrict__ dmaxs, const unsigned int* __restrict__ smaxs,
                   const unsigned int* __restrict__ tmaxs,
                   float* __restrict__ cost) {
    __shared__ float ts0s[T_], ts1s[T_], tths[T_];
    __shared__ int labs[T_], mks[T_];

    const int b = blockIdx.y;
    const int p = blockIdx.x * 256 + threadIdx.x;
    const float w = (float)(imgw_p[0] - 1);
    const float h = (float)(imgh_p[0] - 1);

    if (threadIdx.x < T_) {
        int t = threadIdx.x;
        const float* tr = targets + (size_t)(b * T_ + t) * D_;
        ts0s[t] = tr[2] * h;
        ts1s[t] = tr[3] * w;
        tths[t] = tr[4];
        int lab = (int)tr[1];
        labs[t] = lab < 0 ? 0 : (lab > 1 ? 1 : lab);
        mks[t] = masks[b * T_ + t];
    }
    __syncthreads();
    if (p >= P_) return;

    float dmaxv = fmaxf(__uint_as_float(dmaxs[b]), 1e-8f);
    float smaxv = fmaxf(__uint_as_float(smaxs[b]), 1e-8f);
    float tmaxv = fmaxf(__uint_as_float(tmaxs[b]), 1e-8f);

    const float* pr = preds + (size_t)(b * P_ + p) * D_;
    float fc[2];
#pragma unroll
    for (int c = 0; c < 2; ++c) {
        float x = pr[c];
        float pc = 1.f / (1.f + expf(-x));
        float neg = -logf(1.f - pc + 1e-12f) * 0.75f * pc * pc;
        float pos = -logf(pc + 1e-12f) * 0.25f * (1.f - pc) * (1.f - pc);
        fc[c] = pos - neg;
    }
    float ps0 = pr[2] * h, ps1 = pr[3] * w, pth = pr[4];

#pragma unroll
    for (int t = 0; t < T_; ++t) {
        float d = dist[(size_t)(b * T_ + t) * P_ + p];
        float dsc = 1.f - d / dmaxv + 0.01f;
        float d0 = ps0 - ts0s[t], d1 = ps1 - ts1s[t];
        float sd = sqrtf(d0 * d0 + d1 * d1);
        float ssc = 1.f - sd / smaxv + 0.01f;
        float td = fabsf(pth - tths[t]) * 180.f;
        float tsc = 1.f - td / tmaxv + 0.01f;
        float reg = fmaxf(dsc, 1e-3f) * fmaxf(ssc, 1e-3f) * fmaxf(tsc, 1e-3f);
        float c = -(reg * reg) * 3.f + fc[labs[t]];
        if (mks[t] <= 0) c = BIGC;
        cost[(size_t)(b * T_ + t) * P_ + p] = c;
    }
}

// ---------------- Kernel C: per-(b,t) top-4 + dynamic-k selection ----------------
__global__ void kC(const float* __restrict__ liou, const float* __restrict__ cost,
                   const int* __restrict__ masks, unsigned int* __restrict__ bits) {
    const int gtid = blockIdx.x * blockDim.x + threadIdx.x;
    const int wid = gtid >> 6;        // one wave per (b,t)
    const int lane = threadIdx.x & 63;
    if (wid >= B_ * T_) return;
    const int b = wid / T_, t = wid - b * T_;

    const float* lrow = liou + (size_t)(b * T_ + t) * P_;
    const float* crow = cost + (size_t)(b * T_ + t) * P_;

    float lv[16], cv[16];
#pragma unroll
    for (int i = 0; i < 16; ++i) {
        int p = lane + 64 * i;
        bool ok = p < P_;
        lv[i] = ok ? lrow[p] : -INFINITY;
        cv[i] = ok ? crow[p] : INFINITY;
    }

    float sum = 0.f;
    for (int r = 0; r < 4; ++r) {
        float bv = -INFINITY; int bi = 0x7fffffff;
#pragma unroll
        for (int i = 0; i < 16; ++i) {
            if (lv[i] > bv) { bv = lv[i]; bi = lane + 64 * i; }
        }
        for (int off = 32; off; off >>= 1) {
            float ov = __shfl_xor(bv, off, 64);
            int oi = __shfl_xor(bi, off, 64);
            if (ov > bv || (ov == bv && oi < bi)) { bv = ov; bi = oi; }
        }
        sum += bv;
        if ((bi & 63) == lane) lv[bi >> 6] = -INFINITY;
    }
    int dk = 0;
    if (masks[b * T_ + t] > 0) {
        dk = (int)sum;
        if (dk < 1) dk = 1;
        if (dk > 4) dk = 4;
    }

    int selp[4];
#pragma unroll
    for (int r = 0; r < 4; ++r) {
        float bv = INFINITY; int bi = 0x7fffffff;
#pragma unroll
        for (int i = 0; i < 16; ++i) {
            if (cv[i] < bv) { bv = cv[i]; bi = lane + 64 * i; }
        }
        for (int off = 32; off; off >>= 1) {
            float ov = __shfl_xor(bv, off, 64);
            int oi = __shfl_xor(bi, off, 64);
            if (ov < bv || (ov == bv && oi < bi)) { bv = ov; bi = oi; }
        }
        selp[r] = bi;
        if ((bi & 63) == lane) cv[bi >> 6] = INFINITY;
    }

    if (lane == 0) {
#pragma unroll
        for (int j = 0; j < 4; ++j) {
            if (j < dk) atomicOr(&bits[b * P_ + selp[j]], 1u << t);
        }
    }
}

// ---------------- Kernel D: conflict resolution + output ----------------
__global__ void kD(const unsigned int* __restrict__ bits, const float* __restrict__ cost,
                   int* __restrict__ out) {
    const int idx = blockIdx.x * 256 + threadIdx.x;
    if (idx >= B_ * P_) return;
    const int b = idx / P_, p = idx - b * P_;
    unsigned int m = bits[idx];
    int matched = -1;
    if (m) {
        if (__popc(m) == 1) {
            matched = __ffs(m) - 1;
        } else {
            float best = INFINITY;
#pragma unroll
            for (int t = 0; t < T_; ++t) {
                if ((m >> t) & 1u) {
                    float c = cost[(size_t)(b * T_ + t) * P_ + p];
                    if (c < best) { best = c; matched = t; }
                }
            }
        }
    }
    out[idx] = (matched >= 0) ? 1 : 0;
    out[B_ * P_ + idx] = matched;
}

extern "C" void kernel_launch(void* const* d_in, const int* in_sizes, int n_in,
                              void* d_out, int out_size, void* d_ws, size_t ws_size,
                              hipStream_t stream) {
    const float* preds   = (const float*)d_in[0];
    const float* targets = (const float*)d_in[1];
    const int*   masks   = (const int*)d_in[2];
    const int*   imgw    = (const int*)d_in[3];
    const int*   imgh    = (const int*)d_in[4];
    int* out = (int*)d_out;

    char* ws = (char*)d_ws;
    const size_t SZ = (size_t)B_ * T_ * P_ * sizeof(float);   // 2,048,000 B
    float* dist = (float*)ws;
    float* liou = (float*)(ws + SZ);
    float* cost = (float*)(ws + 2 * SZ);
    unsigned int* dmax = (unsigned int*)(ws + 3 * SZ);        // 32 each
    unsigned int* smax = dmax + 32;
    unsigned int* tmax = dmax + 64;
    unsigned int* bits = (unsigned int*)(ws + 3 * SZ + 512);  // B_*P_ uints

    hipMemsetAsync(ws + 3 * SZ, 0, 512 + (size_t)B_ * P_ * sizeof(unsigned int), stream);

    kA<<<dim3((P_ + 63) / 64, B_), 256, 0, stream>>>(preds, targets, imgw, imgh, dist, liou, dmax, smax, tmax);
    kB<<<dim3(4, B_), 256, 0, stream>>>(preds, targets, masks, imgw, imgh, dist, dmax, smax, tmax, cost);
    kC<<<128, 256, 0, stream>>>(liou, cost, masks, bits);
    kD<<<125, 256, 0, stream>>>(bits, cost, out);
}

// Round 4
// 37.394 us; speedup vs baseline: 3.4586x; 1.2010x over previous
//
#include <hip/hip_runtime.h>
#include <math.h>

#define B_ 32
#define P_ 1000
#define T_ 16
#define D_ 78
#define O_ 72
#define NXB 16            // ceil(P_/64)
#define BIGC 100000000.0f

// ---------------- K1: dist & liou + per-p scalars + per-block partial maxes ----------------
// Identity: per valid element, ovr = 30-|po-to|, union = 30+|po-to|.
// S = sum(m*|po-to|), cnt = sum(m): dist = S/max(cnt,1), liou = (30c-S)/(30c+S+1e-9).
__global__ __launch_bounds__(256) void k1(
        const float* __restrict__ preds, const float* __restrict__ targets,
        const int* __restrict__ imgw_p, const int* __restrict__ imgh_p,
        float* __restrict__ dist, float* __restrict__ liou,
        float4* __restrict__ scal4, float* __restrict__ pths,
        float* __restrict__ pmax) {
    __shared__ float pred_s[64 * 81];          // pad 81 -> conflict-free per-lane rows
    __shared__ float2 tomg[T_ * O_];           // [(g*O+o)*4 + j] = (to*w, mask), t = 4g+j
    __shared__ float cnt_s[T_], clen_s[T_], ts0_s[T_], ts1_s[T_], tth_s[T_];
    __shared__ float red[256];

    const int b = blockIdx.y, bx = blockIdx.x;
    const int p0 = bx * 64;
    const int rows = min(64, P_ - p0);
    const float w = (float)(imgw_p[0] - 1);
    const float h = (float)(imgh_p[0] - 1);
    const float imgwf = (float)imgw_p[0];

    // stage preds rows (coalesced float4); scale col 3 and cols>=6 by w
    {
        const float4* gbase = (const float4*)(preds + ((size_t)b * P_ + p0) * D_);
        const int n4 = rows * D_ / 4;
        for (int i = threadIdx.x; i < n4; i += 256) {
            float4 v = gbase[i];
            int base = i * 4;
            int r = base / D_, c = base - r * D_;
#pragma unroll
            for (int k = 0; k < 4; ++k) {
                int cc = c + k, rr = r;
                if (cc >= D_) { cc -= D_; ++rr; }
                float x = (&v.x)[k];
                if (cc >= 6 || cc == 3) x *= w;
                pred_s[rr * 81 + cc] = x;
            }
        }
    }
    // stage target offsets + masks, packed per (t-group, o)
    for (int i = threadIdx.x; i < T_ * O_; i += 256) {
        int t = i / O_, o = i - t * O_;
        float to = targets[((size_t)b * T_ + t) * D_ + 6 + o] * w;
        float m = (to >= 0.f && to < imgwf) ? 1.f : 0.f;
        tomg[((t >> 2) * O_ + o) * 4 + (t & 3)] = make_float2(to, m);
    }
    __syncthreads();
    if (threadIdx.x < T_) {
        int t = threadIdx.x;
        float c = 0.f;
        for (int o = 0; o < O_; ++o) c += tomg[((t >> 2) * O_ + o) * 4 + (t & 3)].y;
        cnt_s[t] = c;
        clen_s[t] = fmaxf(c, 1.f);
        const float* tr = targets + ((size_t)b * T_ + t) * D_;
        ts0_s[t] = tr[2] * h;
        ts1_s[t] = tr[3] * w;
        tth_s[t] = tr[4];
    }
    __syncthreads();

    const int lane = threadIdx.x & 63;
    const int g = threadIdx.x >> 6;            // wave g handles t = 4g..4g+3
    const int p = p0 + lane;

    float ldm = 0.f, lsm = 0.f, ltm = 0.f;
    if (p < P_) {
        const float* lrow = pred_s + lane * 81;
        float S0 = 0.f, S1 = 0.f, S2 = 0.f, S3 = 0.f;
        const float4* tg4 = (const float4*)(tomg + (size_t)g * O_ * 4);
#pragma unroll 4
        for (int o = 0; o < O_; ++o) {
            float po = lrow[6 + o];
            float4 r0 = tg4[2 * o];            // (to0,m0,to1,m1) - wave-uniform broadcast
            float4 r1 = tg4[2 * o + 1];        // (to2,m2,to3,m3)
            S0 += r0.y * fabsf(po - r0.x);
            S1 += r0.w * fabsf(po - r0.z);
            S2 += r1.y * fabsf(po - r1.x);
            S3 += r1.w * fabsf(po - r1.z);
        }
        float Sv[4] = {S0, S1, S2, S3};
        float ps0 = lrow[2] * h, ps1 = lrow[3], pth = lrow[4];   // col3 pre-scaled by w
#pragma unroll
        for (int j = 0; j < 4; ++j) {
            int t = 4 * g + j;
            float dv = Sv[j] / clen_s[t];
            dist[(size_t)(b * T_ + t) * P_ + p] = dv;
            ldm = fmaxf(ldm, dv);
            float c30 = 30.f * cnt_s[t];
            liou[(size_t)(b * T_ + t) * P_ + p] = (c30 - Sv[j]) / (c30 + Sv[j] + 1e-9f);
            float d0 = ps0 - ts0_s[t], d1 = ps1 - ts1_s[t];
            lsm = fmaxf(lsm, sqrtf(d0 * d0 + d1 * d1));
            ltm = fmaxf(ltm, fabsf(pth - tth_s[t]) * 180.f);
        }
        // first wave also emits the per-p scalars for K2/K3
        if (g == 0) {
            float fc[2];
#pragma unroll
            for (int c = 0; c < 2; ++c) {
                float x = lrow[c];
                float pc = 1.f / (1.f + expf(-x));
                float neg = -logf(1.f - pc + 1e-12f) * 0.75f * pc * pc;
                float pos = -logf(pc + 1e-12f) * 0.25f * (1.f - pc) * (1.f - pc);
                fc[c] = pos - neg;
            }
            scal4[(size_t)b * P_ + p] = make_float4(fc[0], fc[1], ps0, ps1);
            pths[(size_t)b * P_ + p] = pth;
        }
    }

    // block max reductions -> plain stores (no atomics, no init needed)
    red[threadIdx.x] = ldm; __syncthreads();
    for (int s = 128; s; s >>= 1) {
        if (threadIdx.x < s) red[threadIdx.x] = fmaxf(red[threadIdx.x], red[threadIdx.x + s]);
        __syncthreads();
    }
    float m0 = red[0]; __syncthreads();
    red[threadIdx.x] = lsm; __syncthreads();
    for (int s = 128; s; s >>= 1) {
        if (threadIdx.x < s) red[threadIdx.x] = fmaxf(red[threadIdx.x], red[threadIdx.x + s]);
        __syncthreads();
    }
    float m1 = red[0]; __syncthreads();
    red[threadIdx.x] = ltm; __syncthreads();
    for (int s = 128; s; s >>= 1) {
        if (threadIdx.x < s) red[threadIdx.x] = fmaxf(red[threadIdx.x], red[threadIdx.x + s]);
        __syncthreads();
    }
    if (threadIdx.x == 0) {
        float* q = pmax + (size_t)(b * NXB + bx) * 3;
        q[0] = m0; q[1] = m1; q[2] = red[0];
    }
}

// ---------------- K2: cost on the fly + dynamic-k + top-4 selection ----------------
__global__ __launch_bounds__(256) void k2(
        const float* __restrict__ targets, const int* __restrict__ masks,
        const int* __restrict__ imgw_p, const int* __restrict__ imgh_p,
        const float* __restrict__ dist, const float* __restrict__ liou,
        const float4* __restrict__ scal4, const float* __restrict__ pths,
        const float* __restrict__ pmax,
        float* __restrict__ cost, int4* __restrict__ sel) {
    const int wid = blockIdx.x * 4 + (threadIdx.x >> 6);   // one wave per (b,t)
    const int lane = threadIdx.x & 63;
    if (wid >= B_ * T_) return;
    const int b = wid >> 4, t = wid & 15;

    float dm = 0.f, sm = 0.f, tm = 0.f;
    for (int i = 0; i < NXB; ++i) {
        const float* q = pmax + (size_t)(b * NXB + i) * 3;
        dm = fmaxf(dm, q[0]); sm = fmaxf(sm, q[1]); tm = fmaxf(tm, q[2]);
    }
    dm = fmaxf(dm, 1e-8f); sm = fmaxf(sm, 1e-8f); tm = fmaxf(tm, 1e-8f);

    const float w = (float)(imgw_p[0] - 1);
    const float h = (float)(imgh_p[0] - 1);
    const float* tr = targets + (size_t)(b * T_ + t) * D_;
    const float ts0 = tr[2] * h, ts1 = tr[3] * w, tth = tr[4];
    int lab = (int)tr[1]; lab = lab < 0 ? 0 : (lab > 1 ? 1 : lab);
    const int mk = masks[b * T_ + t];

    const float* drow = dist + (size_t)(b * T_ + t) * P_;
    const float* lrow = liou + (size_t)(b * T_ + t) * P_;
    float* crow = cost + (size_t)(b * T_ + t) * P_;
    const float4* s4b = scal4 + (size_t)b * P_;
    const float* ptb = pths + (size_t)b * P_;

    float lv[16], cv[16];
#pragma unroll
    for (int i = 0; i < 16; ++i) {
        int p = lane + 64 * i;
        if (p < P_) {
            float d = drow[p];
            float4 s4 = s4b[p];
            float pth = ptb[p];
            float dsc = 1.f - d / dm + 0.01f;
            float d0 = s4.z - ts0, d1 = s4.w - ts1;
            float ssc = 1.f - sqrtf(d0 * d0 + d1 * d1) / sm + 0.01f;
            float tsc = 1.f - fabsf(pth - tth) * 180.f / tm + 0.01f;
            float reg = fmaxf(dsc, 1e-3f) * fmaxf(ssc, 1e-3f) * fmaxf(tsc, 1e-3f);
            float c = -(reg * reg) * 3.f + (lab ? s4.y : s4.x);
            if (mk <= 0) c = BIGC;
            crow[p] = c;
            cv[i] = c;
            lv[i] = lrow[p];
        } else {
            cv[i] = INFINITY;
            lv[i] = -INFINITY;
        }
    }

    // sum of top-4 liou (wave argmax, 4 rounds)
    float sum = 0.f;
    for (int r = 0; r < 4; ++r) {
        float bv = -INFINITY; int bi = 0x7fffffff;
#pragma unroll
        for (int i = 0; i < 16; ++i) {
            if (lv[i] > bv) { bv = lv[i]; bi = lane + 64 * i; }
        }
        for (int off = 32; off; off >>= 1) {
            float ov = __shfl_xor(bv, off, 64);
            int oi = __shfl_xor(bi, off, 64);
            if (ov > bv || (ov == bv && oi < bi)) { bv = ov; bi = oi; }
        }
        sum += bv;
        if ((bi & 63) == lane) lv[bi >> 6] = -INFINITY;
    }
    int dk = 0;
    if (mk > 0) {
        dk = (int)sum;              // trunc toward zero == astype(int32)
        if (dk < 1) dk = 1;
        if (dk > 4) dk = 4;
    }

    // top-4 lowest cost, tie-break lower p (lax.top_k stable semantics)
    int selp[4];
#pragma unroll
    for (int r = 0; r < 4; ++r) {
        float bv = INFINITY; int bi = 0x7fffffff;
#pragma unroll
        for (int i = 0; i < 16; ++i) {
            if (cv[i] < bv) { bv = cv[i]; bi = lane + 64 * i; }
        }
        for (int off = 32; off; off >>= 1) {
            float ov = __shfl_xor(bv, off, 64);
            int oi = __shfl_xor(bi, off, 64);
            if (ov < bv || (ov == bv && oi < bi)) { bv = ov; bi = oi; }
        }
        selp[r] = bi;
        if ((bi & 63) == lane) cv[bi >> 6] = INFINITY;
    }

    if (lane == 0) {
        sel[wid] = make_int4(dk > 0 ? selp[0] : -1, dk > 1 ? selp[1] : -1,
                             dk > 2 ? selp[2] : -1, dk > 3 ? selp[3] : -1);
    }
}

// ---------------- K3: membership + conflict resolution + output ----------------
__global__ __launch_bounds__(256) void k3(const int4* __restrict__ sel,
                                          const float* __restrict__ cost,
                                          int* __restrict__ out) {
    __shared__ int selE[64];
    const int b = blockIdx.x;
    if (threadIdx.x < 64) selE[threadIdx.x] = ((const int*)sel)[b * 64 + threadIdx.x];
    __syncthreads();

#pragma unroll
    for (int k = 0; k < 4; ++k) {
        int p = k * 256 + threadIdx.x;
        if (p >= P_) continue;
        unsigned int m = 0;
#pragma unroll
        for (int t = 0; t < T_; ++t) {
            bool hit = (selE[4 * t] == p) | (selE[4 * t + 1] == p) |
                       (selE[4 * t + 2] == p) | (selE[4 * t + 3] == p);
            if (hit) m |= 1u << t;
        }
        int matched = -1;
        if (m) {
            if (__popc(m) == 1) {
                matched = __ffs(m) - 1;
            } else {
                float best = INFINITY;
#pragma unroll
                for (int t = 0; t < T_; ++t) {
                    if ((m >> t) & 1u) {
                        float c = cost[(size_t)(b * T_ + t) * P_ + p];
                        if (c < best) { best = c; matched = t; }  // strict <: first-min
                    }
                }
            }
        }
        out[b * P_ + p] = (matched >= 0) ? 1 : 0;
        out[B_ * P_ + b * P_ + p] = matched;
    }
}

extern "C" void kernel_launch(void* const* d_in, const int* in_sizes, int n_in,
                              void* d_out, int out_size, void* d_ws, size_t ws_size,
                              hipStream_t stream) {
    const float* preds   = (const float*)d_in[0];
    const float* targets = (const float*)d_in[1];
    const int*   masks   = (const int*)d_in[2];
    const int*   imgw    = (const int*)d_in[3];
    const int*   imgh    = (const int*)d_in[4];
    int* out = (int*)d_out;

    char* ws = (char*)d_ws;
    const size_t SZ = (size_t)B_ * T_ * P_ * sizeof(float);     // 2,048,000 B
    float*  dist  = (float*)ws;                                  // [B][T][P]
    float*  liou  = (float*)(ws + SZ);                           // [B][T][P]
    float*  cost  = (float*)(ws + 2 * SZ);                       // [B][T][P]
    float4* scal4 = (float4*)(ws + 3 * SZ);                      // [B][P] {fc0,fc1,ps0,ps1}
    float*  pths  = (float*)(ws + 3 * SZ + (size_t)B_ * P_ * 16);// [B][P]
    float*  pmax  = (float*)(ws + 3 * SZ + (size_t)B_ * P_ * 20);// [B][NXB][3]
    int4*   sel   = (int4*)(ws + 3 * SZ + (size_t)B_ * P_ * 20 + (size_t)B_ * NXB * 3 * 4 + 64);

    k1<<<dim3(NXB, B_), 256, 0, stream>>>(preds, targets, imgw, imgh, dist, liou, scal4, pths, pmax);
    k2<<<128, 256, 0, stream>>>(targets, masks, imgw, imgh, dist, liou, scal4, pths, pmax, cost, sel);
    k3<<<B_, 256, 0, stream>>>(sel, cost, out);
}